// Round 11
// baseline (279.486 us; speedup 1.0000x reference)
//
#include <hip/hip_runtime.h>
#include <math.h>

#define NI   32
#define NH   1024
#define NB   1024

// ws layout (floats). g-axis (h2 units) degree-SORTED (suffix skip); h1-axis NATURAL.
//   W1t [32][1056] : W1t[j][s] = m1-masked W1[orig(s)][j], s sorted (stride-padded)
//   b1s [1056]     : sorted b1 (overread lanes masked)
//   b2s [1024]     : sorted b2
//   W3s [64][1024] : m3-masked, sorted columns
//   W2t [1054][1024]: W2t[oh][sg] = m2-masked W2[orig(sg)][oh]; rows natural oh,
//                     +30 pad rows for u-overrun loads (x0.0, poison = finite)
#define W1T_STRIDE 1056
#define OFF_W1T 0
#define OFF_B1S (32 * W1T_STRIDE)          // 33792
#define OFF_B2S (OFF_B1S + W1T_STRIDE)     // 34848
#define OFF_W3S (OFF_B2S + NH)             // 35872
#define OFF_W2T (OFF_W3S + 64 * NH)        // 101408
// total = 101408 + 1054*1024 = 1180704 floats (~4.72 MB)

// degree class d: units h = d, d+31, ... ; d=0 has 34 units, d>=1 has 33.
__device__ __forceinline__ int base_of(int d) { return (d == 0) ? 0 : 33 * d + 1; }

// ---- prep (unchanged from R10; overhead proved launch-dominated, not compute) ----
template <int CNT>
__device__ __forceinline__ void prep_w2_cls(int d, int oh0, const float* __restrict__ W2,
                                            float* __restrict__ ws, int t,
                                            float (*tile)[65]) {
    const int bse = base_of(d);
#pragma unroll 1
    for (int e = t; e < CNT * 64; e += 256) {
        int k = e >> 6, c = e & 63;
        int og = d + 31 * k;
        tile[k][c] = W2[(size_t)og * NH + oh0 + c];
    }
    __syncthreads();
#pragma unroll 1
    for (int e = t; e < 64 * CNT; e += 256) {
        int oh_l = e / CNT;
        int k = e - oh_l * CNT;
        int oh = oh0 + oh_l;
        float v = (d >= (oh % 31)) ? tile[k][oh_l] : 0.0f;
        ws[OFF_W2T + (size_t)oh * NH + bse + k] = v;
    }
}

template <int CNT>
__device__ __forceinline__ void prep_small_cls(int d, const float* __restrict__ W1,
        const float* __restrict__ b1, const float* __restrict__ b2,
        const float* __restrict__ W3, float* __restrict__ ws, int t) {
    const int bse = base_of(d);
#pragma unroll 1
    for (int e = t; e < 64 * CNT; e += 256) {
        int o = e / CNT, k = e - o * CNT;
        int og = d + 31 * k;
        float v = (((o & 31) - 1) >= d) ? W3[(size_t)o * NH + og] : 0.0f;
        ws[OFF_W3S + (size_t)o * NH + bse + k] = v;
    }
#pragma unroll 1
    for (int e = t; e < 32 * CNT; e += 256) {
        int j = e / CNT, k = e - j * CNT;
        int og = d + 31 * k;
        float v = (d >= j) ? W1[og * NI + j] : 0.0f;
        ws[OFF_W1T + j * W1T_STRIDE + bse + k] = v;
    }
    if (t < CNT) {
        int og = d + 31 * t;
        ws[OFF_B1S + bse + t] = b1[og];
        ws[OFF_B2S + bse + t] = b2[og];
    }
}

__global__ __launch_bounds__(256) void prep_all(const float* __restrict__ W1,
        const float* __restrict__ b1, const float* __restrict__ W2,
        const float* __restrict__ b2, const float* __restrict__ W3,
        float* __restrict__ ws) {
    __shared__ float tile[34][65];
    const int bid = blockIdx.x, t = threadIdx.x;
    if (bid < 496) {
        int d = bid >> 4, oh0 = (bid & 15) * 64;
        if (d == 0) prep_w2_cls<34>(0, oh0, W2, ws, t, tile);
        else        prep_w2_cls<33>(d, oh0, W2, ws, t, tile);
    } else {
        int d = bid - 496;
        if (d == 0) prep_small_cls<34>(0, W1, b1, b2, W3, ws, t);
        else        prep_small_cls<33>(d, W1, b1, b2, W3, ws, t);
    }
}

// ---- scan helpers ----
template <int BASE, int N>
__device__ __forceinline__ void consume_grp(float4 (&G)[12], float a0, float a1,
                                            float4& acc0, float4& acc1) {
#pragma unroll
    for (int u = 0; u < N; ++u) {
        float c0 = __shfl(a0, BASE + u, 64), c1 = __shfl(a1, BASE + u, 64);
        acc0.x = fmaf(c0, G[u].x, acc0.x); acc0.y = fmaf(c0, G[u].y, acc0.y);
        acc0.z = fmaf(c0, G[u].z, acc0.z); acc0.w = fmaf(c0, G[u].w, acc0.w);
        acc1.x = fmaf(c1, G[u].x, acc1.x); acc1.y = fmaf(c1, G[u].y, acc1.y);
        acc1.z = fmaf(c1, G[u].z, acc1.z); acc1.w = fmaf(c1, G[u].w, acc1.w);
    }
}

// Block = 2 batch rows x 4 slice-waves (float4/lane). 512 blocks = 2/CU,
// 2 waves/SIMD. Deep pipeline: Q+R (22 loads) issued together at step start;
// P (first group) prefetched CROSS-STEP with register recycling, so every step
// starts with 12 loads resident; blockIdx%3 rotates group order to decorrelate
// same-address L2 bursts across blocks. One barrier/step.
template <int O0, int N0, int O1, int N1, int O2, int N2>
__device__ __forceinline__ void scan_body(
        const float* __restrict__ inputs, const float* __restrict__ b3,
        const float* __restrict__ ws, float* __restrict__ out,
        const int lane, const int w, const int gb, const int row0) {
    __shared__ float part[2][4][4];

    const float* W1t = ws + OFF_W1T;
    const float* b1s = ws + OFF_B1S;
    const float* b2s = ws + OFF_B2S;
    const float* W3s = ws + OFF_W3S;
    const float* W2t = ws + OFF_W2T;

    float4 acc0 = ((const float4*)(b2s + gb))[lane];   // z2 slice, rows 0/1
    float4 acc1 = acc0;
    float xin0 = (lane < NI) ? inputs[row0 * NI + lane] : 0.0f;
    float xin1 = (lane < NI) ? inputs[(row0 + 1) * NI + lane] : 0.0f;
    float b3v  = b3[lane];
    float xr0 = 0.f, xr1 = 0.f, J0 = 0.f, J1 = 0.f;    // x_j in lane j

    // ---- step 0: m3 masks rows 0 and 32 entirely -> p = (b3[0], b3[32]).
    // Uniform compute, no barrier needed.
    {
        float p00 = __shfl(b3v, 0, 64), p01 = __shfl(b3v, NI, 64);
        float e20 = __expf(2.f * fminf(p01, 15.f));
        float ta  = (e20 - 1.f) / (e20 + 1.f);
        float es  = __expf(ta);
        float x0  = fmaf(__shfl(xin0, 0, 64), es, p00);
        float x1  = fmaf(__shfl(xin1, 0, 64), es, p00);
        J0 -= ta; J1 -= ta;
        if (lane == 0) { xr0 = x0; xr1 = x1; }
    }

    float4 P[12];
    {   // prologue: prefetch P (first group) of the i=1 panel (dd=0)
        const float* rb = W2t + gb;
#pragma unroll
        for (int u = 0; u < N0; ++u)
            P[u] = ((const float4*)(rb + (size_t)(O0 + u) * 31 * NH))[lane];
    }

#pragma unroll 1
    for (int i = 1; i < NI; ++i) {
        const int dd   = i - 1;
        const int goff = (dd == 0) ? 0 : (33 * dd + 1);
        const int cnt  = (i == 1) ? 34 : 33;
        const bool doB  = (gb + 256 > goff);
        const bool doC  = (gb < 33 * i + 1);
        const bool doBn = (i < NI - 1) && (gb + 256 > 33 * i + 1);

        float4 wa = make_float4(0, 0, 0, 0), wb = make_float4(0, 0, 0, 0);
        if (doC) {
            wa = ((const float4*)(W3s + (size_t)i * NH + gb))[lane];
            wb = ((const float4*)(W3s + (size_t)(NI + i) * NH + gb))[lane];
        }

        if (doB) {
            const float* rb = W2t + (size_t)dd * NH + gb;   // panel row u: oh = dd+31u
            float4 Q[12], R[12];
#pragma unroll
            for (int u = 0; u < N1; ++u)
                Q[u] = ((const float4*)(rb + (size_t)(O1 + u) * 31 * NH))[lane];
#pragma unroll
            for (int u = 0; u < N2; ++u)
                R[u] = ((const float4*)(rb + (size_t)(O2 + u) * 31 * NH))[lane];
            __builtin_amdgcn_sched_barrier(0);

            // ---- Phase A (2 rows): fixed 32 taps; j>=i taps are exact zeros
            const int su = goff + lane;
            float bz = b1s[su];
            float w1v[32];
#pragma unroll
            for (int j = 0; j < 32; ++j) w1v[j] = W1t[j * W1T_STRIDE + su];
            float zA0 = bz, zA1 = 0, zA2 = 0, zA3 = 0;
            float zB0 = bz, zB1 = 0, zB2 = 0, zB3 = 0;
#pragma unroll
            for (int j = 0; j < 32; j += 4) {
                zA0 = fmaf(__shfl(xr0, j + 0, 64), w1v[j + 0], zA0);
                zB0 = fmaf(__shfl(xr1, j + 0, 64), w1v[j + 0], zB0);
                zA1 = fmaf(__shfl(xr0, j + 1, 64), w1v[j + 1], zA1);
                zB1 = fmaf(__shfl(xr1, j + 1, 64), w1v[j + 1], zB1);
                zA2 = fmaf(__shfl(xr0, j + 2, 64), w1v[j + 2], zA2);
                zB2 = fmaf(__shfl(xr1, j + 2, 64), w1v[j + 2], zB2);
                zA3 = fmaf(__shfl(xr0, j + 3, 64), w1v[j + 3], zA3);
                zB3 = fmaf(__shfl(xr1, j + 3, 64), w1v[j + 3], zB3);
            }
            const bool ok = lane < cnt;
            float a0 = ok ? fmaxf((zA0 + zA1) + (zA2 + zA3), 0.f) : 0.f;
            float a1 = ok ? fmaxf((zB0 + zB1) + (zB2 + zB3), 0.f) : 0.f;
            __builtin_amdgcn_sched_barrier(0);

            consume_grp<O0, N0>(P, a0, a1, acc0, acc1);    // P resident since last step
            __builtin_amdgcn_sched_barrier(0);
            if (doBn) {             // cross-step prefetch: reuse P's registers now
                const float* rbn = W2t + (size_t)i * NH + gb;
#pragma unroll
                for (int u = 0; u < N0; ++u)
                    P[u] = ((const float4*)(rbn + (size_t)(O0 + u) * 31 * NH))[lane];
            }
            __builtin_amdgcn_sched_barrier(0);
            consume_grp<O1, N1>(Q, a0, a1, acc0, acc1);
            __builtin_amdgcn_sched_barrier(0);
            consume_grp<O2, N2>(R, a0, a1, acc0, acc1);
        }

        // ---- Phase C: slice partials (W3s zeros beyond prefix keep it exact)
        float s00 = 0, s01 = 0, s10 = 0, s11 = 0;
        if (doC) {
            float hx, hy, hz, hw;
            hx = fmaxf(acc0.x, 0.f); hy = fmaxf(acc0.y, 0.f);
            hz = fmaxf(acc0.z, 0.f); hw = fmaxf(acc0.w, 0.f);
            s00 = fmaf(wa.x, hx, fmaf(wa.y, hy, fmaf(wa.z, hz, wa.w * hw)));
            s01 = fmaf(wb.x, hx, fmaf(wb.y, hy, fmaf(wb.z, hz, wb.w * hw)));
            hx = fmaxf(acc1.x, 0.f); hy = fmaxf(acc1.y, 0.f);
            hz = fmaxf(acc1.z, 0.f); hw = fmaxf(acc1.w, 0.f);
            s10 = fmaf(wa.x, hx, fmaf(wa.y, hy, fmaf(wa.z, hz, wa.w * hw)));
            s11 = fmaf(wb.x, hx, fmaf(wb.y, hy, fmaf(wb.z, hz, wb.w * hw)));
#pragma unroll
            for (int m = 32; m >= 1; m >>= 1) {
                s00 += __shfl_xor(s00, m, 64); s01 += __shfl_xor(s01, m, 64);
                s10 += __shfl_xor(s10, m, 64); s11 += __shfl_xor(s11, m, 64);
            }
        }
        if (lane == 0)
            *((float4*)&part[i & 1][w][0]) = make_float4(s00, s01, s10, s11);
        __syncthreads();

        // ---- combine (replicated in all lanes/waves -> identical xr update)
        const float* pb = &part[i & 1][0][0];
        float4 q0 = ((const float4*)pb)[0], q1 = ((const float4*)pb)[1];
        float4 q2 = ((const float4*)pb)[2], q3 = ((const float4*)pb)[3];
        float bi  = __shfl(b3v, i, 64);
        float bia = __shfl(b3v, NI + i, 64);
        float p00 = ((q0.x + q1.x) + (q2.x + q3.x)) + bi;
        float p01 = ((q0.y + q1.y) + (q2.y + q3.y)) + bia;
        float p10 = ((q0.z + q1.z) + (q2.z + q3.z)) + bi;
        float p11 = ((q0.w + q1.w) + (q2.w + q3.w)) + bia;
        float e20 = __expf(2.f * fminf(p01, 15.f));     // tanh; exact sat both ends
        float ta0 = (e20 - 1.f) / (e20 + 1.f);
        float x0  = fmaf(__shfl(xin0, i, 64), __expf(ta0), p00);
        float e21 = __expf(2.f * fminf(p11, 15.f));
        float ta1 = (e21 - 1.f) / (e21 + 1.f);
        float x1  = fmaf(__shfl(xin1, i, 64), __expf(ta1), p10);
        J0 -= ta0; J1 -= ta1;
        if (lane == i) { xr0 = x0; xr1 = x1; }
    }

    if (w == 0) {
        if (lane < NI) {
            out[row0 * NI + lane]       = xr0;
            out[(row0 + 1) * NI + lane] = xr1;
        }
        if (lane == 0) {
            out[NB * NI + row0]     = J0;
            out[NB * NI + row0 + 1] = J1;
        }
    }
}

__global__ __launch_bounds__(256, 2) void made_scan(
        const float* __restrict__ inputs,
        const float* __restrict__ b3,
        const float* __restrict__ ws,
        float* __restrict__ out) {
    const int lane = threadIdx.x & 63;
    const int w    = threadIdx.x >> 6;
    const int pairity = ((blockIdx.x >> 8) ^ blockIdx.x) & 1;
    const int q    = w ^ (pairity * 3);     // slice rotation (R10, kept)
    const int gb   = q * 256;
    const int row0 = blockIdx.x * 2;

    // group-order rotation: decorrelate same-address panel bursts across blocks
    switch (blockIdx.x % 3) {
        case 0:  scan_body< 0, 12, 12, 12, 24, 10>(inputs, b3, ws, out, lane, w, gb, row0); break;
        case 1:  scan_body<12, 12, 24, 10,  0, 12>(inputs, b3, ws, out, lane, w, gb, row0); break;
        default: scan_body<24, 10,  0, 12, 12, 12>(inputs, b3, ws, out, lane, w, gb, row0); break;
    }
}

extern "C" void kernel_launch(void* const* d_in, const int* in_sizes, int n_in,
                              void* d_out, int out_size, void* d_ws, size_t ws_size,
                              hipStream_t stream) {
    const float* inputs = (const float*)d_in[0];
    const float* W1     = (const float*)d_in[1];
    const float* b1     = (const float*)d_in[2];
    const float* W2     = (const float*)d_in[3];
    const float* b2     = (const float*)d_in[4];
    const float* W3     = (const float*)d_in[5];
    const float* b3     = (const float*)d_in[6];
    float* out = (float*)d_out;
    float* ws  = (float*)d_ws;

    prep_all<<<527, 256, 0, stream>>>(W1, b1, W2, b2, W3, ws);
    made_scan<<<NB / 2, 256, 0, stream>>>(inputs, b3, ws, out);
}

// Round 12
// 221.711 us; speedup vs baseline: 1.2606x; 1.2606x over previous
//
#include <hip/hip_runtime.h>
#include <math.h>

#define NI   32
#define NH   1024
#define NB   1024

// ws layout (floats). g-axis (h2 units) degree-SORTED (suffix skip); h1-axis NATURAL.
//   W1t [32][1056] : W1t[j][s] = m1-masked W1[orig(s)][j], s sorted (stride-padded)
//   b1s [1056]     : sorted b1 (overread lanes masked)
//   b2s [1024]     : sorted b2
//   W3s [64][1024] : m3-masked, sorted columns
//   W2t [1054][1024]: W2t[oh][sg] = m2-masked W2[orig(sg)][oh]; rows natural oh,
//                     +30 pad rows for u-overrun loads (x0.0, poison = finite)
#define W1T_STRIDE 1056
#define OFF_W1T 0
#define OFF_B1S (32 * W1T_STRIDE)          // 33792
#define OFF_B2S (OFF_B1S + W1T_STRIDE)     // 34848
#define OFF_W3S (OFF_B2S + NH)             // 35872
#define OFF_W2T (OFF_W3S + 64 * NH)        // 101408
// total = 101408 + 1054*1024 = 1180704 floats (~4.72 MB)

// degree class d: units h = d, d+31, ... ; d=0 has 34 units, d>=1 has 33.
__device__ __forceinline__ int base_of(int d) { return (d == 0) ? 0 : 33 * d + 1; }

// Raw workgroup barrier: drain LDS (lgkmcnt) ONLY — outstanding global LOADS
// stay in flight across the barrier. simm16 = 0xC07F: vmcnt=63, expcnt=7,
// lgkmcnt=0. (This is the whole point of R12: __syncthreads() emits
// s_waitcnt vmcnt(0) lgkmcnt(0) and drains the cross-step prefetch.)
__device__ __forceinline__ void barrier_lgkm() {
    __builtin_amdgcn_s_waitcnt(0xC07F);
    __builtin_amdgcn_s_barrier();
}

// ---- prep (unchanged from R10; overhead proved launch-dominated) ----
template <int CNT>
__device__ __forceinline__ void prep_w2_cls(int d, int oh0, const float* __restrict__ W2,
                                            float* __restrict__ ws, int t,
                                            float (*tile)[65]) {
    const int bse = base_of(d);
#pragma unroll 1
    for (int e = t; e < CNT * 64; e += 256) {
        int k = e >> 6, c = e & 63;
        int og = d + 31 * k;
        tile[k][c] = W2[(size_t)og * NH + oh0 + c];
    }
    __syncthreads();
#pragma unroll 1
    for (int e = t; e < 64 * CNT; e += 256) {
        int oh_l = e / CNT;
        int k = e - oh_l * CNT;
        int oh = oh0 + oh_l;
        float v = (d >= (oh % 31)) ? tile[k][oh_l] : 0.0f;
        ws[OFF_W2T + (size_t)oh * NH + bse + k] = v;
    }
}

template <int CNT>
__device__ __forceinline__ void prep_small_cls(int d, const float* __restrict__ W1,
        const float* __restrict__ b1, const float* __restrict__ b2,
        const float* __restrict__ W3, float* __restrict__ ws, int t) {
    const int bse = base_of(d);
#pragma unroll 1
    for (int e = t; e < 64 * CNT; e += 256) {
        int o = e / CNT, k = e - o * CNT;
        int og = d + 31 * k;
        float v = (((o & 31) - 1) >= d) ? W3[(size_t)o * NH + og] : 0.0f;
        ws[OFF_W3S + (size_t)o * NH + bse + k] = v;
    }
#pragma unroll 1
    for (int e = t; e < 32 * CNT; e += 256) {
        int j = e / CNT, k = e - j * CNT;
        int og = d + 31 * k;
        float v = (d >= j) ? W1[og * NI + j] : 0.0f;
        ws[OFF_W1T + j * W1T_STRIDE + bse + k] = v;
    }
    if (t < CNT) {
        int og = d + 31 * t;
        ws[OFF_B1S + bse + t] = b1[og];
        ws[OFF_B2S + bse + t] = b2[og];
    }
}

__global__ __launch_bounds__(256) void prep_all(const float* __restrict__ W1,
        const float* __restrict__ b1, const float* __restrict__ W2,
        const float* __restrict__ b2, const float* __restrict__ W3,
        float* __restrict__ ws) {
    __shared__ float tile[34][65];
    const int bid = blockIdx.x, t = threadIdx.x;
    if (bid < 496) {
        int d = bid >> 4, oh0 = (bid & 15) * 64;
        if (d == 0) prep_w2_cls<34>(0, oh0, W2, ws, t, tile);
        else        prep_w2_cls<33>(d, oh0, W2, ws, t, tile);
    } else {
        int d = bid - 496;
        if (d == 0) prep_small_cls<34>(0, W1, b1, b2, W3, ws, t);
        else        prep_small_cls<33>(d, W1, b1, b2, W3, ws, t);
    }
}

// ---- scan helpers ----
template <int BASE, int N, int M>
__device__ __forceinline__ void consume_grp(float4 (&G)[M], float a0, float a1,
                                            float4& acc0, float4& acc1) {
#pragma unroll
    for (int u = 0; u < N; ++u) {
        float c0 = __shfl(a0, BASE + u, 64), c1 = __shfl(a1, BASE + u, 64);
        acc0.x = fmaf(c0, G[u].x, acc0.x); acc0.y = fmaf(c0, G[u].y, acc0.y);
        acc0.z = fmaf(c0, G[u].z, acc0.z); acc0.w = fmaf(c0, G[u].w, acc0.w);
        acc1.x = fmaf(c1, G[u].x, acc1.x); acc1.y = fmaf(c1, G[u].y, acc1.y);
        acc1.z = fmaf(c1, G[u].z, acc1.z); acc1.w = fmaf(c1, G[u].w, acc1.w);
    }
}

// Block = 2 batch rows x 4 slice-waves (float4/lane). 512 blocks = 2/CU,
// 2 waves/SIMD. Pipeline: P (panel rows 0..11) prefetched CROSS-STEP, issued
// before the lgkm-only barrier so it stays in flight through barrier+combine+
// next A; G2 at step start; G3 after A. One raw barrier/step.
__global__ __launch_bounds__(256, 2) void made_scan(
        const float* __restrict__ inputs,
        const float* __restrict__ b3,
        const float* __restrict__ ws,
        float* __restrict__ out) {
    __shared__ float part[2][4][4];     // [buf][wave][s00,s01,s10,s11]

    const int lane = threadIdx.x & 63;
    const int w    = threadIdx.x >> 6;
    const int pairity = ((blockIdx.x >> 8) ^ blockIdx.x) & 1;
    const int q    = w ^ (pairity * 3); // slice rotation (R10, kept: +2%)
    const int gb   = q * 256;           // sorted-g slice base
    const int row0 = blockIdx.x * 2;

    const float* W1t = ws + OFF_W1T;
    const float* b1s = ws + OFF_B1S;
    const float* b2s = ws + OFF_B2S;
    const float* W3s = ws + OFF_W3S;
    const float* W2t = ws + OFF_W2T;

    float4 acc0 = ((const float4*)(b2s + gb))[lane];   // z2 slice, rows 0/1
    float4 acc1 = acc0;
    float xin0 = (lane < NI) ? inputs[row0 * NI + lane] : 0.0f;
    float xin1 = (lane < NI) ? inputs[(row0 + 1) * NI + lane] : 0.0f;
    float b3v  = b3[lane];
    float xr0 = 0.f, xr1 = 0.f, J0 = 0.f, J1 = 0.f;    // x_j in lane j

    // ---- step 0: m3 masks rows 0 and 32 entirely -> p = (b3[0], b3[32]).
    // Uniform compute, no barrier needed. (proven exact in R11: absmax 1.9e-6)
    {
        float p00 = __shfl(b3v, 0, 64), p01 = __shfl(b3v, NI, 64);
        float e20 = __expf(2.f * fminf(p01, 15.f));
        float ta  = (e20 - 1.f) / (e20 + 1.f);
        float es  = __expf(ta);
        float x0  = fmaf(__shfl(xin0, 0, 64), es, p00);
        float x1  = fmaf(__shfl(xin1, 0, 64), es, p00);
        J0 -= ta; J1 -= ta;
        if (lane == 0) { xr0 = x0; xr1 = x1; }
    }

    float4 P[12];
    {   // prologue: prefetch P (rows 0..11) of the i=1 panel (dd=0)
        const float* rb = W2t + gb;
#pragma unroll
        for (int u = 0; u < 12; ++u)
            P[u] = ((const float4*)(rb + (size_t)u * 31 * NH))[lane];
    }

#pragma unroll 1
    for (int i = 1; i < NI; ++i) {
        const int dd   = i - 1;
        const int goff = (dd == 0) ? 0 : (33 * dd + 1);
        const int cnt  = (i == 1) ? 34 : 33;
        const bool doB  = (gb + 256 > goff);
        const bool doC  = (gb < 33 * i + 1);
        const bool doBn = (i < NI - 1) && (gb + 256 > 33 * i + 1);

        float4 wa = make_float4(0, 0, 0, 0), wb = make_float4(0, 0, 0, 0);
        if (doC) {
            wa = ((const float4*)(W3s + (size_t)i * NH + gb))[lane];
            wb = ((const float4*)(W3s + (size_t)(NI + i) * NH + gb))[lane];
        }

        if (doB) {
            const float* rb = W2t + (size_t)dd * NH + gb;   // panel row u: oh = dd+31u
            float4 G2[12];
#pragma unroll
            for (int u = 0; u < 12; ++u)
                G2[u] = ((const float4*)(rb + (size_t)(12 + u) * 31 * NH))[lane];
            __builtin_amdgcn_sched_barrier(0);

            // ---- Phase A (2 rows): fixed 32 taps; j>=i taps are exact zeros
            const int su = goff + lane;
            float bz = b1s[su];
            float w1v[32];
#pragma unroll
            for (int j = 0; j < 32; ++j) w1v[j] = W1t[j * W1T_STRIDE + su];
            float zA0 = bz, zA1 = 0, zA2 = 0, zA3 = 0;
            float zB0 = bz, zB1 = 0, zB2 = 0, zB3 = 0;
#pragma unroll
            for (int j = 0; j < 32; j += 4) {
                zA0 = fmaf(__shfl(xr0, j + 0, 64), w1v[j + 0], zA0);
                zB0 = fmaf(__shfl(xr1, j + 0, 64), w1v[j + 0], zB0);
                zA1 = fmaf(__shfl(xr0, j + 1, 64), w1v[j + 1], zA1);
                zB1 = fmaf(__shfl(xr1, j + 1, 64), w1v[j + 1], zB1);
                zA2 = fmaf(__shfl(xr0, j + 2, 64), w1v[j + 2], zA2);
                zB2 = fmaf(__shfl(xr1, j + 2, 64), w1v[j + 2], zB2);
                zA3 = fmaf(__shfl(xr0, j + 3, 64), w1v[j + 3], zA3);
                zB3 = fmaf(__shfl(xr1, j + 3, 64), w1v[j + 3], zB3);
            }
            const bool ok = lane < cnt;
            float a0 = ok ? fmaxf((zA0 + zA1) + (zA2 + zA3), 0.f) : 0.f;
            float a1 = ok ? fmaxf((zB0 + zB1) + (zB2 + zB3), 0.f) : 0.f;
            __builtin_amdgcn_sched_barrier(0);

            float4 G3[10];
#pragma unroll
            for (int u = 0; u < 10; ++u)
                G3[u] = ((const float4*)(rb + (size_t)(24 + u) * 31 * NH))[lane];
            __builtin_amdgcn_sched_barrier(0);

            consume_grp< 0, 12>(P,  a0, a1, acc0, acc1);   // resident since last step
            __builtin_amdgcn_sched_barrier(0);
            consume_grp<12, 12>(G2, a0, a1, acc0, acc1);
            __builtin_amdgcn_sched_barrier(0);
            consume_grp<24, 10>(G3, a0, a1, acc0, acc1);
        }

        // ---- Phase C: slice partials (W3s zeros beyond prefix keep it exact)
        float s00 = 0, s01 = 0, s10 = 0, s11 = 0;
        if (doC) {
            float hx, hy, hz, hw;
            hx = fmaxf(acc0.x, 0.f); hy = fmaxf(acc0.y, 0.f);
            hz = fmaxf(acc0.z, 0.f); hw = fmaxf(acc0.w, 0.f);
            s00 = fmaf(wa.x, hx, fmaf(wa.y, hy, fmaf(wa.z, hz, wa.w * hw)));
            s01 = fmaf(wb.x, hx, fmaf(wb.y, hy, fmaf(wb.z, hz, wb.w * hw)));
            hx = fmaxf(acc1.x, 0.f); hy = fmaxf(acc1.y, 0.f);
            hz = fmaxf(acc1.z, 0.f); hw = fmaxf(acc1.w, 0.f);
            s10 = fmaf(wa.x, hx, fmaf(wa.y, hy, fmaf(wa.z, hz, wa.w * hw)));
            s11 = fmaf(wb.x, hx, fmaf(wb.y, hy, fmaf(wb.z, hz, wb.w * hw)));
#pragma unroll
            for (int m = 32; m >= 1; m >>= 1) {
                s00 += __shfl_xor(s00, m, 64); s01 += __shfl_xor(s01, m, 64);
                s10 += __shfl_xor(s10, m, 64); s11 += __shfl_xor(s11, m, 64);
            }
        }
        if (lane == 0)
            *((float4*)&part[i & 1][w][0]) = make_float4(s00, s01, s10, s11);

        // ---- cross-step prefetch: reload P with next panel's rows 0..11.
        // Issued BEFORE the lgkm-only barrier -> stays in flight through
        // barrier + combine + next step's A (~1500 cyc of cover).
        if (doBn) {
            const float* rbn = W2t + (size_t)i * NH + gb;
#pragma unroll
            for (int u = 0; u < 12; ++u)
                P[u] = ((const float4*)(rbn + (size_t)u * 31 * NH))[lane];
        }
        barrier_lgkm();                     // drains LDS only, not global loads

        // ---- combine (replicated in all lanes/waves -> identical xr update)
        const float* pb = &part[i & 1][0][0];
        float4 q0 = ((const float4*)pb)[0], q1 = ((const float4*)pb)[1];
        float4 q2 = ((const float4*)pb)[2], q3 = ((const float4*)pb)[3];
        float bi  = __shfl(b3v, i, 64);
        float bia = __shfl(b3v, NI + i, 64);
        float p00 = ((q0.x + q1.x) + (q2.x + q3.x)) + bi;
        float p01 = ((q0.y + q1.y) + (q2.y + q3.y)) + bia;
        float p10 = ((q0.z + q1.z) + (q2.z + q3.z)) + bi;
        float p11 = ((q0.w + q1.w) + (q2.w + q3.w)) + bia;
        float e20 = __expf(2.f * fminf(p01, 15.f));     // tanh; exact sat both ends
        float ta0 = (e20 - 1.f) / (e20 + 1.f);
        float x0  = fmaf(__shfl(xin0, i, 64), __expf(ta0), p00);
        float e21 = __expf(2.f * fminf(p11, 15.f));
        float ta1 = (e21 - 1.f) / (e21 + 1.f);
        float x1  = fmaf(__shfl(xin1, i, 64), __expf(ta1), p10);
        J0 -= ta0; J1 -= ta1;
        if (lane == i) { xr0 = x0; xr1 = x1; }
    }

    if (w == 0) {
        if (lane < NI) {
            out[row0 * NI + lane]       = xr0;
            out[(row0 + 1) * NI + lane] = xr1;
        }
        if (lane == 0) {
            out[NB * NI + row0]     = J0;
            out[NB * NI + row0 + 1] = J1;
        }
    }
}

extern "C" void kernel_launch(void* const* d_in, const int* in_sizes, int n_in,
                              void* d_out, int out_size, void* d_ws, size_t ws_size,
                              hipStream_t stream) {
    const float* inputs = (const float*)d_in[0];
    const float* W1     = (const float*)d_in[1];
    const float* b1     = (const float*)d_in[2];
    const float* W2     = (const float*)d_in[3];
    const float* b2     = (const float*)d_in[4];
    const float* W3     = (const float*)d_in[5];
    const float* b3     = (const float*)d_in[6];
    float* out = (float*)d_out;
    float* ws  = (float*)d_ws;

    prep_all<<<527, 256, 0, stream>>>(W1, b1, W2, b2, W3, ws);
    made_scan<<<NB / 2, 256, 0, stream>>>(inputs, b3, ws, out);
}

// Round 13
// 187.613 us; speedup vs baseline: 1.4897x; 1.1817x over previous
//
#include <hip/hip_runtime.h>
#include <math.h>

#define NI   32
#define NH   1024
#define NB   1024

// ws layout. g-axis (h2) degree-SORTED; h1-axis natural. W2/W1 stored as BF16.
//   fp32: b1s[1056] @0, b2s[1024] @1056, W3s[64][1024] @2080
//   W1B  (uint)  @67616 : W1B[k][su] = bf16(W1m[j=2k][su]) | bf16(W1m[2k+1][su])<<16
//   PB   (uint4) @84512 : panel dd, pair u2, sg-quad Q, halves r=0/1:
//                 16B block = { sg0|sg1<<16, sg2|sg3<<16 } x { unit 2u2, 2u2+1 }
#define OFF_B1S 0
#define OFF_B2S 1056
#define OFF_W3S 2080
#define OFF_W1B 67616            // float-index (4B units)
#define OFF_PB  84512            // float-index; PB block idx = (dd*17+u2)*256 + Q
// PB total: 31*17*256*16B = 2.16MB; overall ws use ~2.5MB.

__device__ __forceinline__ int base_of(int d) { return (d == 0) ? 0 : 33 * d + 1; }

__device__ __forceinline__ unsigned short f2bf(float f) {   // RNE bf16
    unsigned u = __float_as_uint(f);
    return (unsigned short)((u + 0x7FFFu + ((u >> 16) & 1u)) >> 16);
}
__device__ __forceinline__ float bflo(unsigned u) { return __uint_as_float(u << 16); }
__device__ __forceinline__ float bfhi(unsigned u) { return __uint_as_float(u & 0xFFFF0000u); }

// ---- prep: W2 class-chunk LDS transpose -> bf16 packed panel (2B stores,
// same store count as fp32 version; masked zeros cover boundary quads) ----
template <int CNT>
__device__ __forceinline__ void prep_w2_cls(int d, int oh0, const float* __restrict__ W2,
                                            unsigned short* __restrict__ pb16, int t,
                                            float (*tile)[65]) {
    const int bse = base_of(d);
#pragma unroll 1
    for (int e = t; e < CNT * 64; e += 256) {
        int k = e >> 6, c = e & 63;
        int og = d + 31 * k;
        tile[k][c] = W2[(size_t)og * NH + oh0 + c];
    }
    __syncthreads();
#pragma unroll 1
    for (int e = t; e < 64 * CNT; e += 256) {
        int oh_l = e / CNT;
        int k = e - oh_l * CNT;
        int oh = oh0 + oh_l;
        int dd = oh % 31, u = oh / 31;
        int sg = bse + k;
        float v = (d >= dd) ? tile[k][oh_l] : 0.0f;
        // ushort addr: 16B block (dd*17+u2)*256+(sg>>2), half (u&1), elem sg&3
        size_t a = (size_t)((dd * 17 + (u >> 1)) * 256 + (sg >> 2)) * 8
                 + (u & 1) * 4 + (sg & 3);
        pb16[a] = f2bf(v);
    }
}

template <int CNT>
__device__ __forceinline__ void prep_small_cls(int d, const float* __restrict__ W1,
        const float* __restrict__ b1, const float* __restrict__ b2,
        const float* __restrict__ W3, float* __restrict__ ws, int t) {
    const int bse = base_of(d);
    unsigned short* w1b16 = (unsigned short*)(ws + OFF_W1B);
#pragma unroll 1
    for (int e = t; e < 64 * CNT; e += 256) {       // W3s fp32 (exact epilogue)
        int o = e / CNT, k = e - o * CNT;
        int og = d + 31 * k;
        float v = (((o & 31) - 1) >= d) ? W3[(size_t)o * NH + og] : 0.0f;
        ws[OFF_W3S + (size_t)o * NH + bse + k] = v;
    }
#pragma unroll 1
    for (int e = t; e < 32 * CNT; e += 256) {       // W1 -> bf16 packed pairs
        int j = e / CNT, k = e - j * CNT;
        int og = d + 31 * k;
        int su = bse + k;
        float v = (d >= j) ? W1[og * NI + j] : 0.0f;
        w1b16[(size_t)((j >> 1) * 1056 + su) * 2 + (j & 1)] = f2bf(v);
    }
    if (t < CNT) {
        int og = d + 31 * t;
        ws[OFF_B1S + bse + t] = b1[og];
        ws[OFF_B2S + bse + t] = b2[og];
    }
}

__global__ __launch_bounds__(256) void prep_all(const float* __restrict__ W1,
        const float* __restrict__ b1, const float* __restrict__ W2,
        const float* __restrict__ b2, const float* __restrict__ W3,
        float* __restrict__ ws) {
    __shared__ float tile[34][65];
    const int bid = blockIdx.x, t = threadIdx.x;
    unsigned short* pb16 = (unsigned short*)(ws + OFF_PB);
    if (bid < 496) {
        int d = bid >> 4, oh0 = (bid & 15) * 64;
        if (d == 0) prep_w2_cls<34>(0, oh0, W2, pb16, t, tile);
        else        prep_w2_cls<33>(d, oh0, W2, pb16, t, tile);
    } else {
        int d = bid - 496;
        if (d == 0) prep_small_cls<34>(0, W1, b1, b2, W3, ws, t);
        else        prep_small_cls<33>(d, W1, b1, b2, W3, ws, t);
    }
}

// consume one pair-load: units 2u2 (ca*), 2u2+1 (cb*); 8 unpack + 16 FMA
__device__ __forceinline__ void consume_pair(uint4 g, float ca0, float ca1,
                                             float cb0, float cb1,
                                             float4& acc0, float4& acc1) {
    float f0 = bflo(g.x), f1 = bfhi(g.x), f2 = bflo(g.y), f3 = bfhi(g.y);
    float f4 = bflo(g.z), f5 = bfhi(g.z), f6 = bflo(g.w), f7 = bfhi(g.w);
    acc0.x = fmaf(ca0, f0, acc0.x); acc0.y = fmaf(ca0, f1, acc0.y);
    acc0.z = fmaf(ca0, f2, acc0.z); acc0.w = fmaf(ca0, f3, acc0.w);
    acc1.x = fmaf(ca1, f0, acc1.x); acc1.y = fmaf(ca1, f1, acc1.y);
    acc1.z = fmaf(ca1, f2, acc1.z); acc1.w = fmaf(ca1, f3, acc1.w);
    acc0.x = fmaf(cb0, f4, acc0.x); acc0.y = fmaf(cb0, f5, acc0.y);
    acc0.z = fmaf(cb0, f6, acc0.z); acc0.w = fmaf(cb0, f7, acc0.w);
    acc1.x = fmaf(cb1, f4, acc1.x); acc1.y = fmaf(cb1, f5, acc1.y);
    acc1.z = fmaf(cb1, f6, acc1.z); acc1.w = fmaf(cb1, f7, acc1.w);
}

// Block = 2 batch rows x 4 slice-waves (float4/lane). 512 blocks = 2/CU,
// 2 waves/SIMD. bf16 panels: 17 pair-loads/step (9+8 fenced groups), bf16 W1
// in 2x8 dword chunks. R10 skeleton otherwise (slice rotation, 1 barrier/step).
__global__ __launch_bounds__(256, 2) void made_scan(
        const float* __restrict__ inputs,
        const float* __restrict__ b3,
        const float* __restrict__ ws,
        float* __restrict__ out) {
    __shared__ float part[2][4][4];

    const int lane = threadIdx.x & 63;
    const int w    = threadIdx.x >> 6;
    const int pairity = ((blockIdx.x >> 8) ^ blockIdx.x) & 1;
    const int q    = w ^ (pairity * 3);
    const int gb   = q * 256;
    const int row0 = blockIdx.x * 2;

    const float* b1s = ws + OFF_B1S;
    const float* b2s = ws + OFF_B2S;
    const float* W3s = ws + OFF_W3S;
    const unsigned* W1B = (const unsigned*)(ws + OFF_W1B);
    const uint4*    PB  = (const uint4*)(ws + OFF_PB);

    float4 acc0 = ((const float4*)(b2s + gb))[lane];
    float4 acc1 = acc0;
    float xin0 = (lane < NI) ? inputs[row0 * NI + lane] : 0.0f;
    float xin1 = (lane < NI) ? inputs[(row0 + 1) * NI + lane] : 0.0f;
    float b3v  = b3[lane];
    float xr0 = 0.f, xr1 = 0.f, J0 = 0.f, J1 = 0.f;

    // step 0: rows 0/32 of W3 fully masked -> p = (b3[0], b3[32])
    {
        float p00 = __shfl(b3v, 0, 64), p01 = __shfl(b3v, NI, 64);
        float e20 = __expf(2.f * fminf(p01, 15.f));
        float ta  = (e20 - 1.f) / (e20 + 1.f);
        float es  = __expf(ta);
        float x0  = fmaf(__shfl(xin0, 0, 64), es, p00);
        float x1  = fmaf(__shfl(xin1, 0, 64), es, p00);
        J0 -= ta; J1 -= ta;
        if (lane == 0) { xr0 = x0; xr1 = x1; }
    }

#pragma unroll 1
    for (int i = 1; i < NI; ++i) {
        const int dd   = i - 1;
        const int goff = base_of(dd);
        const int cnt  = (i == 1) ? 34 : 33;
        const bool doB = (gb + 256 > goff);
        const bool doC = (gb < 33 * i + 1);

        float4 wa = make_float4(0, 0, 0, 0), wb = make_float4(0, 0, 0, 0);
        if (doC) {
            wa = ((const float4*)(W3s + (size_t)i * NH + gb))[lane];
            wb = ((const float4*)(W3s + (size_t)(NI + i) * NH + gb))[lane];
        }

        if (doB) {
            const uint4* pbase = PB + (size_t)(dd * 17) * 256 + (gb >> 2) + lane;
            uint4 G1[9];
#pragma unroll
            for (int u2 = 0; u2 < 9; ++u2) G1[u2] = pbase[u2 * 256];
            __builtin_amdgcn_sched_barrier(0);

            // Phase A: 32 taps from bf16 pairs, W1B in 2x8 chunks
            const int su = goff + lane;
            float bz = b1s[su];
            float zA0 = bz, zA1 = 0, zA2 = 0, zA3 = 0;
            float zB0 = bz, zB1 = 0, zB2 = 0, zB3 = 0;
            unsigned wk[8];
#pragma unroll
            for (int k = 0; k < 8; ++k) wk[k] = W1B[k * 1056 + su];
            __builtin_amdgcn_sched_barrier(0);
#pragma unroll
            for (int k = 0; k < 8; ++k) {
                float w0 = bflo(wk[k]), w1 = bfhi(wk[k]);
                zA0 = fmaf(__shfl(xr0, 2 * k, 64), w0, zA0);
                zB0 = fmaf(__shfl(xr1, 2 * k, 64), w0, zB0);
                zA1 = fmaf(__shfl(xr0, 2 * k + 1, 64), w1, zA1);
                zB1 = fmaf(__shfl(xr1, 2 * k + 1, 64), w1, zB1);
            }
#pragma unroll
            for (int k = 0; k < 8; ++k) wk[k] = W1B[(8 + k) * 1056 + su];
            __builtin_amdgcn_sched_barrier(0);
#pragma unroll
            for (int k = 0; k < 8; ++k) {
                float w0 = bflo(wk[k]), w1 = bfhi(wk[k]);
                zA2 = fmaf(__shfl(xr0, 16 + 2 * k, 64), w0, zA2);
                zB2 = fmaf(__shfl(xr1, 16 + 2 * k, 64), w0, zB2);
                zA3 = fmaf(__shfl(xr0, 17 + 2 * k, 64), w1, zA3);
                zB3 = fmaf(__shfl(xr1, 17 + 2 * k, 64), w1, zB3);
            }
            const bool ok = lane < cnt;
            float a0 = ok ? fmaxf((zA0 + zA1) + (zA2 + zA3), 0.f) : 0.f;
            float a1 = ok ? fmaxf((zB0 + zB1) + (zB2 + zB3), 0.f) : 0.f;
            __builtin_amdgcn_sched_barrier(0);

            uint4 G2[8];
#pragma unroll
            for (int u2 = 0; u2 < 8; ++u2) G2[u2] = pbase[(9 + u2) * 256];
            __builtin_amdgcn_sched_barrier(0);
#pragma unroll
            for (int u2 = 0; u2 < 9; ++u2)
                consume_pair(G1[u2], __shfl(a0, 2 * u2, 64), __shfl(a1, 2 * u2, 64),
                             __shfl(a0, 2 * u2 + 1, 64), __shfl(a1, 2 * u2 + 1, 64),
                             acc0, acc1);
            __builtin_amdgcn_sched_barrier(0);
#pragma unroll
            for (int u2 = 0; u2 < 8; ++u2)
                consume_pair(G2[u2], __shfl(a0, 18 + 2 * u2, 64), __shfl(a1, 18 + 2 * u2, 64),
                             __shfl(a0, 19 + 2 * u2, 64), __shfl(a1, 19 + 2 * u2, 64),
                             acc0, acc1);
        }

        // Phase C (fp32 W3; zeros beyond prefix keep it exact)
        float s00 = 0, s01 = 0, s10 = 0, s11 = 0;
        if (doC) {
            float hx, hy, hz, hw;
            hx = fmaxf(acc0.x, 0.f); hy = fmaxf(acc0.y, 0.f);
            hz = fmaxf(acc0.z, 0.f); hw = fmaxf(acc0.w, 0.f);
            s00 = fmaf(wa.x, hx, fmaf(wa.y, hy, fmaf(wa.z, hz, wa.w * hw)));
            s01 = fmaf(wb.x, hx, fmaf(wb.y, hy, fmaf(wb.z, hz, wb.w * hw)));
            hx = fmaxf(acc1.x, 0.f); hy = fmaxf(acc1.y, 0.f);
            hz = fmaxf(acc1.z, 0.f); hw = fmaxf(acc1.w, 0.f);
            s10 = fmaf(wa.x, hx, fmaf(wa.y, hy, fmaf(wa.z, hz, wa.w * hw)));
            s11 = fmaf(wb.x, hx, fmaf(wb.y, hy, fmaf(wb.z, hz, wb.w * hw)));
#pragma unroll
            for (int m = 32; m >= 1; m >>= 1) {
                s00 += __shfl_xor(s00, m, 64); s01 += __shfl_xor(s01, m, 64);
                s10 += __shfl_xor(s10, m, 64); s11 += __shfl_xor(s11, m, 64);
            }
        }
        if (lane == 0)
            *((float4*)&part[i & 1][w][0]) = make_float4(s00, s01, s10, s11);
        __syncthreads();

        const float* pb = &part[i & 1][0][0];
        float4 q0 = ((const float4*)pb)[0], q1 = ((const float4*)pb)[1];
        float4 q2 = ((const float4*)pb)[2], q3 = ((const float4*)pb)[3];
        float bi  = __shfl(b3v, i, 64);
        float bia = __shfl(b3v, NI + i, 64);
        float p00 = ((q0.x + q1.x) + (q2.x + q3.x)) + bi;
        float p01 = ((q0.y + q1.y) + (q2.y + q3.y)) + bia;
        float p10 = ((q0.z + q1.z) + (q2.z + q3.z)) + bi;
        float p11 = ((q0.w + q1.w) + (q2.w + q3.w)) + bia;
        float e20 = __expf(2.f * fminf(p01, 15.f));
        float ta0 = (e20 - 1.f) / (e20 + 1.f);
        float x0  = fmaf(__shfl(xin0, i, 64), __expf(ta0), p00);
        float e21 = __expf(2.f * fminf(p11, 15.f));
        float ta1 = (e21 - 1.f) / (e21 + 1.f);
        float x1  = fmaf(__shfl(xin1, i, 64), __expf(ta1), p10);
        J0 -= ta0; J1 -= ta1;
        if (lane == i) { xr0 = x0; xr1 = x1; }
    }

    if (w == 0) {
        if (lane < NI) {
            out[row0 * NI + lane]       = xr0;
            out[(row0 + 1) * NI + lane] = xr1;
        }
        if (lane == 0) {
            out[NB * NI + row0]     = J0;
            out[NB * NI + row0 + 1] = J1;
        }
    }
}

extern "C" void kernel_launch(void* const* d_in, const int* in_sizes, int n_in,
                              void* d_out, int out_size, void* d_ws, size_t ws_size,
                              hipStream_t stream) {
    const float* inputs = (const float*)d_in[0];
    const float* W1     = (const float*)d_in[1];
    const float* b1     = (const float*)d_in[2];
    const float* W2     = (const float*)d_in[3];
    const float* b2     = (const float*)d_in[4];
    const float* W3     = (const float*)d_in[5];
    const float* b3     = (const float*)d_in[6];
    float* out = (float*)d_out;
    float* ws  = (float*)d_ws;

    prep_all<<<527, 256, 0, stream>>>(W1, b1, W2, b2, W3, ws);
    made_scan<<<NB / 2, 256, 0, stream>>>(inputs, b3, ws, out);
}

// Round 14
// 167.050 us; speedup vs baseline: 1.6731x; 1.1231x over previous
//
#include <hip/hip_runtime.h>
#include <math.h>

#define NI   32
#define NH   1024
#define NB   1024

// ws layout. g-axis (h2) degree-SORTED; h1-axis natural. W2/W1 stored as BF16.
//   fp32: b1s[1056] @0, b2s[1024] @1056, W3s[64][1024] @2080
//   W1B  (uint)  @67616 : W1B[k][su] = bf16(W1m[j=2k][su]) | bf16(W1m[2k+1][su])<<16
//   PB   (uint4) @84512 : panel dd, pair u2, sg-quad Q, halves r=0/1
#define OFF_B1S 0
#define OFF_B2S 1056
#define OFF_W3S 2080
#define OFF_W1B 67616            // float-index (4B units)
#define OFF_PB  84512            // float-index; PB block idx = (dd*17+u2)*256 + Q

__device__ __forceinline__ int base_of(int d) { return (d == 0) ? 0 : 33 * d + 1; }

__device__ __forceinline__ unsigned short f2bf(float f) {   // RNE bf16
    unsigned u = __float_as_uint(f);
    return (unsigned short)((u + 0x7FFFu + ((u >> 16) & 1u)) >> 16);
}
__device__ __forceinline__ float bflo(unsigned u) { return __uint_as_float(u << 16); }
__device__ __forceinline__ float bfhi(unsigned u) { return __uint_as_float(u & 0xFFFF0000u); }

// ---- prep (identical to R13) ----
template <int CNT>
__device__ __forceinline__ void prep_w2_cls(int d, int oh0, const float* __restrict__ W2,
                                            unsigned short* __restrict__ pb16, int t,
                                            float (*tile)[65]) {
    const int bse = base_of(d);
#pragma unroll 1
    for (int e = t; e < CNT * 64; e += 256) {
        int k = e >> 6, c = e & 63;
        int og = d + 31 * k;
        tile[k][c] = W2[(size_t)og * NH + oh0 + c];
    }
    __syncthreads();
#pragma unroll 1
    for (int e = t; e < 64 * CNT; e += 256) {
        int oh_l = e / CNT;
        int k = e - oh_l * CNT;
        int oh = oh0 + oh_l;
        int dd = oh % 31, u = oh / 31;
        int sg = bse + k;
        float v = (d >= dd) ? tile[k][oh_l] : 0.0f;
        size_t a = (size_t)((dd * 17 + (u >> 1)) * 256 + (sg >> 2)) * 8
                 + (u & 1) * 4 + (sg & 3);
        pb16[a] = f2bf(v);
    }
}

template <int CNT>
__device__ __forceinline__ void prep_small_cls(int d, const float* __restrict__ W1,
        const float* __restrict__ b1, const float* __restrict__ b2,
        const float* __restrict__ W3, float* __restrict__ ws, int t) {
    const int bse = base_of(d);
    unsigned short* w1b16 = (unsigned short*)(ws + OFF_W1B);
#pragma unroll 1
    for (int e = t; e < 64 * CNT; e += 256) {
        int o = e / CNT, k = e - o * CNT;
        int og = d + 31 * k;
        float v = (((o & 31) - 1) >= d) ? W3[(size_t)o * NH + og] : 0.0f;
        ws[OFF_W3S + (size_t)o * NH + bse + k] = v;
    }
#pragma unroll 1
    for (int e = t; e < 32 * CNT; e += 256) {
        int j = e / CNT, k = e - j * CNT;
        int og = d + 31 * k;
        int su = bse + k;
        float v = (d >= j) ? W1[og * NI + j] : 0.0f;
        w1b16[(size_t)((j >> 1) * 1056 + su) * 2 + (j & 1)] = f2bf(v);
    }
    if (t < CNT) {
        int og = d + 31 * t;
        ws[OFF_B1S + bse + t] = b1[og];
        ws[OFF_B2S + bse + t] = b2[og];
    }
}

__global__ __launch_bounds__(256) void prep_all(const float* __restrict__ W1,
        const float* __restrict__ b1, const float* __restrict__ W2,
        const float* __restrict__ b2, const float* __restrict__ W3,
        float* __restrict__ ws) {
    __shared__ float tile[34][65];
    const int bid = blockIdx.x, t = threadIdx.x;
    unsigned short* pb16 = (unsigned short*)(ws + OFF_PB);
    if (bid < 496) {
        int d = bid >> 4, oh0 = (bid & 15) * 64;
        if (d == 0) prep_w2_cls<34>(0, oh0, W2, pb16, t, tile);
        else        prep_w2_cls<33>(d, oh0, W2, pb16, t, tile);
    } else {
        int d = bid - 496;
        if (d == 0) prep_small_cls<34>(0, W1, b1, b2, W3, ws, t);
        else        prep_small_cls<33>(d, W1, b1, b2, W3, ws, t);
    }
}

// consume one bf16 pair-load; coefficients from a 16B broadcast LDS read:
// av = { a0[2u2], a1[2u2], a0[2u2+1], a1[2u2+1] }
__device__ __forceinline__ void consume_pair(uint4 g, float4 av,
                                             float4& acc0, float4& acc1) {
    float f0 = bflo(g.x), f1 = bfhi(g.x), f2 = bflo(g.y), f3 = bfhi(g.y);
    float f4 = bflo(g.z), f5 = bfhi(g.z), f6 = bflo(g.w), f7 = bfhi(g.w);
    acc0.x = fmaf(av.x, f0, acc0.x); acc0.y = fmaf(av.x, f1, acc0.y);
    acc0.z = fmaf(av.x, f2, acc0.z); acc0.w = fmaf(av.x, f3, acc0.w);
    acc1.x = fmaf(av.y, f0, acc1.x); acc1.y = fmaf(av.y, f1, acc1.y);
    acc1.z = fmaf(av.y, f2, acc1.z); acc1.w = fmaf(av.y, f3, acc1.w);
    acc0.x = fmaf(av.z, f4, acc0.x); acc0.y = fmaf(av.z, f5, acc0.y);
    acc0.z = fmaf(av.z, f6, acc0.z); acc0.w = fmaf(av.z, f7, acc0.w);
    acc1.x = fmaf(av.w, f4, acc1.x); acc1.y = fmaf(av.w, f5, acc1.y);
    acc1.z = fmaf(av.w, f6, acc1.z); acc1.w = fmaf(av.w, f7, acc1.w);
}

// Block = 2 batch rows x 4 slice-waves (float4/lane). 512 blocks = 2/CU.
// R14: ALL broadcast __shfl (ds_bpermute, ~100cyc serial) replaced by
// uniform-address LDS reads: per-wave private xs[] (x taps, 16 b128 reads),
// per-wave a1S[] (consume coeffs, 17 b128 reads), staged b3S/xinS.
__global__ __launch_bounds__(256, 2) void made_scan(
        const float* __restrict__ inputs,
        const float* __restrict__ b3,
        const float* __restrict__ ws,
        float* __restrict__ out) {
    __shared__ float xsS[4][2][36];     // per-wave private x (row-major, pad 36)
    __shared__ float a1S[4][36][2];     // per-wave private a1 [unit][row]
    __shared__ float part[2][4][4];
    __shared__ float b3S[64];
    __shared__ float xinS[2][NI];

    const int lane = threadIdx.x & 63;
    const int w    = threadIdx.x >> 6;
    const int pairity = ((blockIdx.x >> 8) ^ blockIdx.x) & 1;
    const int q    = w ^ (pairity * 3);
    const int gb   = q * 256;
    const int row0 = blockIdx.x * 2;

    const float* b1s = ws + OFF_B1S;
    const float* b2s = ws + OFF_B2S;
    const float* W3s = ws + OFF_W3S;
    const unsigned* W1B = (const unsigned*)(ws + OFF_W1B);
    const uint4*    PB  = (const uint4*)(ws + OFF_PB);

    float4 acc0 = ((const float4*)(b2s + gb))[lane];
    float4 acc1 = acc0;
    float J0 = 0.f, J1 = 0.f;

    // init: stage b3/xin; zero private xs
    if (w == 0) {
        b3S[lane] = b3[lane];
        if (lane < NI) {
            xinS[0][lane] = inputs[row0 * NI + lane];
            xinS[1][lane] = inputs[(row0 + 1) * NI + lane];
        }
    }
    {
        float* px = &xsS[w][0][0];
        for (int k = lane; k < 72; k += 64) px[k] = 0.f;
    }
    __syncthreads();

    // step 0: W3 rows 0/32 fully masked -> p = (b3[0], b3[32])
    {
        float p00 = b3S[0], p01 = b3S[NI];
        float e20 = __expf(2.f * fminf(p01, 15.f));
        float ta  = (e20 - 1.f) / (e20 + 1.f);
        float es  = __expf(ta);
        float x0  = fmaf(xinS[0][0], es, p00);
        float x1  = fmaf(xinS[1][0], es, p00);
        J0 -= ta; J1 -= ta;
        if (lane == 0) { xsS[w][0][0] = x0; xsS[w][1][0] = x1; }
    }

#pragma unroll 1
    for (int i = 1; i < NI; ++i) {
        const int dd   = i - 1;
        const int goff = base_of(dd);
        const int cnt  = (i == 1) ? 34 : 33;
        const bool doB = (gb + 256 > goff);
        const bool doC = (gb < 33 * i + 1);

        float4 wa = make_float4(0, 0, 0, 0), wb = make_float4(0, 0, 0, 0);
        if (doC) {
            wa = ((const float4*)(W3s + (size_t)i * NH + gb))[lane];
            wb = ((const float4*)(W3s + (size_t)(NI + i) * NH + gb))[lane];
        }

        if (doB) {
            const uint4* pbase = PB + (size_t)(dd * 17) * 256 + (gb >> 2) + lane;
            uint4 G1[9];
#pragma unroll
            for (int u2 = 0; u2 < 9; ++u2) G1[u2] = pbase[u2 * 256];
            __builtin_amdgcn_sched_barrier(0);

            // Phase A: 32 taps; x from private LDS (b128 broadcast), W1 bf16.
            // Taps j>=i have weight exactly 0 and xs[j]=0 -> exact.
            const int su = goff + lane;
            float bz = b1s[su];
            unsigned wk[16];
#pragma unroll
            for (int k = 0; k < 16; ++k) wk[k] = W1B[k * 1056 + su];
            float zA0 = bz, zA1 = 0, zA2 = 0, zA3 = 0;
            float zB0 = bz, zB1 = 0, zB2 = 0, zB3 = 0;
#pragma unroll
            for (int j4 = 0; j4 < 8; ++j4) {
                float4 xq0 = *(const float4*)&xsS[w][0][4 * j4];
                float4 xq1 = *(const float4*)&xsS[w][1][4 * j4];
                float w0 = bflo(wk[2 * j4]),     w1 = bfhi(wk[2 * j4]);
                float w2 = bflo(wk[2 * j4 + 1]), w3 = bfhi(wk[2 * j4 + 1]);
                zA0 = fmaf(xq0.x, w0, zA0); zB0 = fmaf(xq1.x, w0, zB0);
                zA1 = fmaf(xq0.y, w1, zA1); zB1 = fmaf(xq1.y, w1, zB1);
                zA2 = fmaf(xq0.z, w2, zA2); zB2 = fmaf(xq1.z, w2, zB2);
                zA3 = fmaf(xq0.w, w3, zA3); zB3 = fmaf(xq1.w, w3, zB3);
            }
            const bool ok = lane < cnt;
            float a0 = ok ? fmaxf((zA0 + zA1) + (zA2 + zA3), 0.f) : 0.f;
            float a1 = ok ? fmaxf((zB0 + zB1) + (zB2 + zB3), 0.f) : 0.f;
            if (lane < 36) {                 // publish to own-wave a1S
                float2 v = make_float2(a0, a1);
                *(float2*)&a1S[w][lane][0] = v;
            }
            __builtin_amdgcn_sched_barrier(0);

            uint4 G2[8];
#pragma unroll
            for (int u2 = 0; u2 < 8; ++u2) G2[u2] = pbase[(9 + u2) * 256];
            __builtin_amdgcn_sched_barrier(0);
#pragma unroll
            for (int u2 = 0; u2 < 9; ++u2)
                consume_pair(G1[u2], *(const float4*)&a1S[w][2 * u2][0], acc0, acc1);
            __builtin_amdgcn_sched_barrier(0);
#pragma unroll
            for (int u2 = 0; u2 < 8; ++u2)
                consume_pair(G2[u2], *(const float4*)&a1S[w][18 + 2 * u2][0], acc0, acc1);
        }

        // Phase C (fp32 W3; zeros beyond prefix keep it exact)
        float s00 = 0, s01 = 0, s10 = 0, s11 = 0;
        if (doC) {
            float hx, hy, hz, hw;
            hx = fmaxf(acc0.x, 0.f); hy = fmaxf(acc0.y, 0.f);
            hz = fmaxf(acc0.z, 0.f); hw = fmaxf(acc0.w, 0.f);
            s00 = fmaf(wa.x, hx, fmaf(wa.y, hy, fmaf(wa.z, hz, wa.w * hw)));
            s01 = fmaf(wb.x, hx, fmaf(wb.y, hy, fmaf(wb.z, hz, wb.w * hw)));
            hx = fmaxf(acc1.x, 0.f); hy = fmaxf(acc1.y, 0.f);
            hz = fmaxf(acc1.z, 0.f); hw = fmaxf(acc1.w, 0.f);
            s10 = fmaf(wa.x, hx, fmaf(wa.y, hy, fmaf(wa.z, hz, wa.w * hw)));
            s11 = fmaf(wb.x, hx, fmaf(wb.y, hy, fmaf(wb.z, hz, wb.w * hw)));
#pragma unroll
            for (int m = 32; m >= 1; m >>= 1) {
                s00 += __shfl_xor(s00, m, 64); s01 += __shfl_xor(s01, m, 64);
                s10 += __shfl_xor(s10, m, 64); s11 += __shfl_xor(s11, m, 64);
            }
        }
        if (lane == 0)
            *((float4*)&part[i & 1][w][0]) = make_float4(s00, s01, s10, s11);
        __syncthreads();

        // combine — replicated in every wave; x published to own-wave xs only
        const float* pb = &part[i & 1][0][0];
        float4 q0 = ((const float4*)pb)[0], q1 = ((const float4*)pb)[1];
        float4 q2 = ((const float4*)pb)[2], q3 = ((const float4*)pb)[3];
        float bi  = b3S[i];
        float bia = b3S[NI + i];
        float p00 = ((q0.x + q1.x) + (q2.x + q3.x)) + bi;
        float p01 = ((q0.y + q1.y) + (q2.y + q3.y)) + bia;
        float p10 = ((q0.z + q1.z) + (q2.z + q3.z)) + bi;
        float p11 = ((q0.w + q1.w) + (q2.w + q3.w)) + bia;
        float e20 = __expf(2.f * fminf(p01, 15.f));
        float ta0 = (e20 - 1.f) / (e20 + 1.f);
        float x0  = fmaf(xinS[0][i], __expf(ta0), p00);
        float e21 = __expf(2.f * fminf(p11, 15.f));
        float ta1 = (e21 - 1.f) / (e21 + 1.f);
        float x1  = fmaf(xinS[1][i], __expf(ta1), p10);
        J0 -= ta0; J1 -= ta1;
        if (lane == 0) { xsS[w][0][i] = x0; xsS[w][1][i] = x1; }
    }

    if (w == 0) {
        if (lane < NI) {
            out[row0 * NI + lane]       = xsS[0][0][lane];
            out[(row0 + 1) * NI + lane] = xsS[0][1][lane];
        }
        if (lane == 0) {
            out[NB * NI + row0]     = J0;
            out[NB * NI + row0 + 1] = J1;
        }
    }
}

extern "C" void kernel_launch(void* const* d_in, const int* in_sizes, int n_in,
                              void* d_out, int out_size, void* d_ws, size_t ws_size,
                              hipStream_t stream) {
    const float* inputs = (const float*)d_in[0];
    const float* W1     = (const float*)d_in[1];
    const float* b1     = (const float*)d_in[2];
    const float* W2     = (const float*)d_in[3];
    const float* b2     = (const float*)d_in[4];
    const float* W3     = (const float*)d_in[5];
    const float* b3     = (const float*)d_in[6];
    float* out = (float*)d_out;
    float* ws  = (float*)d_ws;

    prep_all<<<527, 256, 0, stream>>>(W1, b1, W2, b2, W3, ws);
    made_scan<<<NB / 2, 256, 0, stream>>>(inputs, b3, ws, out);
}